// Round 1
// baseline (729.426 us; speedup 1.0000x reference)
//
#include <hip/hip_runtime.h>

#define NC 100000
#define NF 400000
#define NE 1600000
#define NT (NC + NF)            // 500000 combined nodes
#define C  64

// ============================================================================
// CSR build, v2: two-level.
//  Level 1 (k_partition): one scan of each edge list, LDS-ranked 16-way
//    partition by dst range into contiguous (bdst, bsw) bucket arrays.
//    Per-block per-bucket runs (~1.5KB) are written concurrently -> lines
//    complete in L2 fast -> no write amplification.
//  Level 2 (k_hist_bkt / k_place_bkt): per-bucket, XCD-mapped (bucket%8).
//    Bucket rec slice ~0.8MB + cnt slice <=100KB stay resident in the 4MB
//    XCD L2; streaming bucket reads use nontemporal loads (evict-first) so
//    they cannot displace partially-written rec lines. Writeback ~= 25.6MB
//    useful bytes instead of the previous 214MB.
// Coarse phase: 16 buckets x 6250 nodes. Fine phase: 16 buckets x 25000.
// Bucket buffer (19.2MB) aliases h's region (h is written only later).
// ============================================================================

__global__ __launch_bounds__(256) void k_bktcnt(
    const int* __restrict__ cd, const int* __restrict__ pd,
    int* __restrict__ bktCnt)
{
    __shared__ int l[32];
    int tid = threadIdx.x;
    if (tid < 32) l[tid] = 0;
    __syncthreads();
    int stride = gridDim.x * 256;
    for (int e = blockIdx.x * 256 + tid; e < NE; e += stride) {
        atomicAdd(&l[cd[e] / 6250], 1);
        atomicAdd(&l[16 + pd[e] / 25000], 1);
    }
    __syncthreads();
    if (tid < 32) atomicAdd(&bktCnt[tid], l[tid]);
}

__global__ void k_bktscan(const int* __restrict__ bktCnt,
                          int* __restrict__ baseC, int* __restrict__ baseF,
                          int* __restrict__ curC, int* __restrict__ curF)
{
    if (threadIdx.x == 0) {
        int s = 0;
        for (int i = 0; i < 16; ++i) { baseC[i] = s; curC[i] = s; s += bktCnt[i]; }
        baseC[16] = s;
        s = 0;
        for (int i = 0; i < 16; ++i) { baseF[i] = s; curF[i] = s; s += bktCnt[16 + i]; }
        baseF[16] = s;
    }
}

// One tile of 2048 edges per block. Phase 1: LDS histogram of the tile.
// Phase 2: reserve a contiguous global run per bucket (one atomic per
// bucket per block), then rank edges via LDS cursor and write.
template<int NDIV>
__global__ __launch_bounds__(256) void k_partition(
    const int* __restrict__ dst, const int* __restrict__ src,
    const float* __restrict__ w, int* __restrict__ bktCur,
    int* __restrict__ bdst, int2* __restrict__ bsw)
{
    __shared__ int lcnt[16];
    int tid = threadIdx.x;
    int e0 = blockIdx.x * 2048;
    if (tid < 16) lcnt[tid] = 0;
    __syncthreads();
    int rd[8]; int rs[8]; float rw[8];
    #pragma unroll
    for (int i = 0; i < 8; ++i) {
        int e = e0 + i * 256 + tid;
        if (e < NE) {
            rd[i] = dst[e]; rs[i] = src[e]; rw[i] = w[e];
            atomicAdd(&lcnt[rd[i] / NDIV], 1);
        } else rd[i] = -1;
    }
    __syncthreads();
    if (tid < 16) lcnt[tid] = atomicAdd(&bktCur[tid], lcnt[tid]);
    __syncthreads();
    #pragma unroll
    for (int i = 0; i < 8; ++i) {
        if (rd[i] >= 0) {
            int b = rd[i] / NDIV;
            int p = atomicAdd(&lcnt[b], 1);
            bdst[p] = rd[i];
            bsw[p]  = make_int2(rs[i], __float_as_int(rw[i]));
        }
    }
}

// Per-bucket node histogram; bucket = blockIdx&15 -> XCD bucket%8 so the
// cnt slice stays in one XCD's L2.
__global__ __launch_bounds__(256) void k_hist_bkt(
    const int* __restrict__ bdst, const int* __restrict__ bbase,
    int* __restrict__ cnt, int doff)
{
    int b = blockIdx.x & 15;
    int lo = bbase[b], hi = bbase[b + 1];
    int stride = (gridDim.x >> 4) * 256;
    for (int i = lo + (blockIdx.x >> 4) * 256 + threadIdx.x; i < hi; i += stride)
        atomicAdd(&cnt[doff + bdst[i]], 1);
}

// Per-bucket place. Streaming reads are nontemporal (evict-first) so the
// ~0.8MB rec slice + cnt slice stay L2-resident until lines are complete.
__global__ __launch_bounds__(256) void k_place_bkt(
    const int* __restrict__ bdst, const int2* __restrict__ bsw,
    const int* __restrict__ bbase, int doff,
    int* __restrict__ cursor, int2* __restrict__ rec)
{
    int b = blockIdx.x & 15;
    int lo = bbase[b], hi = bbase[b + 1];
    int stride = (gridDim.x >> 4) * 256;
    for (int i = lo + (blockIdx.x >> 4) * 256 + threadIdx.x; i < hi; i += stride) {
        int d = __builtin_nontemporal_load(&bdst[i]);
        unsigned long long sw =
            __builtin_nontemporal_load((const unsigned long long*)&bsw[i]);
        int p = atomicAdd(&cursor[doff + d], 1);
        rec[p] = make_int2((int)(unsigned)(sw & 0xffffffffull), (int)(sw >> 32));
    }
}

// ---------------- Scan ----------------
__global__ __launch_bounds__(256) void k_chunk_sum(
    const int* __restrict__ cnt, int n, int* __restrict__ chunks)
{
    __shared__ int sd[256];
    int t = threadIdx.x;
    int base = blockIdx.x * 1024 + t * 4;
    int s = 0;
    #pragma unroll
    for (int i = 0; i < 4; ++i) if (base + i < n) s += cnt[base + i];
    sd[t] = s; __syncthreads();
    for (int off = 128; off > 0; off >>= 1) {
        if (t < off) sd[t] += sd[t + off];
        __syncthreads();
    }
    if (t == 0) chunks[blockIdx.x] = sd[0];
}

__global__ __launch_bounds__(512) void k_scan_chunks(
    const int* __restrict__ chunks, int* __restrict__ chunkoff, int nChunks)
{
    __shared__ int sd[512];
    int t = threadIdx.x;
    int v = (t < nChunks) ? chunks[t] : 0;
    sd[t] = v; __syncthreads();
    for (int off = 1; off < 512; off <<= 1) {
        int tv = sd[t];
        if (t >= off) tv += sd[t - off];
        __syncthreads();
        sd[t] = tv; __syncthreads();
    }
    if (t < nChunks) chunkoff[t] = sd[t] - v;   // exclusive
}

__global__ __launch_bounds__(256) void k_scan_final(
    const int* __restrict__ cnt, const int* __restrict__ chunkoff,
    int* __restrict__ start, int n, int nE, int base)
{
    __shared__ int sd[256];
    int t = threadIdx.x;
    int bidx = blockIdx.x * 1024 + t * 4;
    int v[4];
    #pragma unroll
    for (int i = 0; i < 4; ++i) v[i] = (bidx + i < n) ? cnt[bidx + i] : 0;
    int tsum = v[0] + v[1] + v[2] + v[3];
    sd[t] = tsum; __syncthreads();
    for (int off = 1; off < 256; off <<= 1) {
        int tv = sd[t];
        if (t >= off) tv += sd[t - off];
        __syncthreads();
        sd[t] = tv; __syncthreads();
    }
    int off = base + chunkoff[blockIdx.x] + sd[t] - tsum;
    #pragma unroll
    for (int i = 0; i < 4; ++i) {
        if (bidx + i < n) { start[bidx + i] = off; off += v[i]; }
    }
    if (blockIdx.x == 0 && t == 0) start[n] = base + nE;
}

// cursor <- start  (place consumes cursor, gathers keep start)
__global__ __launch_bounds__(256) void k_copy(
    const int* __restrict__ src, int* __restrict__ dst, int n)
{
    int i = blockIdx.x * 256 + threadIdx.x;
    if (i < n) dst[i] = src[i];
}

// ---------------- Gathers (unchanged) ----------------
__global__ __launch_bounds__(256) void k_gather_coarse(
    const float* __restrict__ x, const int2* __restrict__ rec,
    const int* __restrict__ start, float* __restrict__ agg)
{
    int tid = threadIdx.x;
    int lane = tid & 63;
    int q = lane >> 4;
    int c4 = (lane & 15) << 2;
    int wv = (blockIdx.x * 256 + tid) >> 6;
    int nW = gridDim.x * 4;
    for (int n = wv; n < NC; n += nW) {
        int s = start[n], e = start[n + 1];
        float ax = 0.f, ay = 0.f, az = 0.f, aw = 0.f;
        for (int j = s + 2 * q; j < e; j += 8) {
            int2 r0 = rec[j];
            int j1 = j + 1;
            int2 r1 = (j1 < e) ? rec[j1] : make_int2(0, 0);
            float4 v0 = *(const float4*)(x + (size_t)r0.x * C + c4);
            float w0 = __int_as_float(r0.y);
            ax = fmaf(w0, v0.x, ax); ay = fmaf(w0, v0.y, ay);
            az = fmaf(w0, v0.z, az); aw = fmaf(w0, v0.w, aw);
            if (j1 < e) {
                float4 v1 = *(const float4*)(x + (size_t)r1.x * C + c4);
                float w1 = __int_as_float(r1.y);
                ax = fmaf(w1, v1.x, ax); ay = fmaf(w1, v1.y, ay);
                az = fmaf(w1, v1.z, az); aw = fmaf(w1, v1.w, aw);
            }
        }
        ax += __shfl_xor(ax, 16); ay += __shfl_xor(ay, 16);
        az += __shfl_xor(az, 16); aw += __shfl_xor(aw, 16);
        ax += __shfl_xor(ax, 32); ay += __shfl_xor(ay, 32);
        az += __shfl_xor(az, 32); aw += __shfl_xor(aw, 32);
        if (q == 0)
            *(float4*)(agg + (size_t)n * C + c4) = make_float4(ax, ay, az, aw);
    }
}

__global__ __launch_bounds__(256) void k_gemm_ip(
    float* __restrict__ h, const float* __restrict__ W, const float* __restrict__ b)
{
    int tid = threadIdx.x;
    int lane = tid & 63;
    float wreg[64];
    #pragma unroll
    for (int k = 0; k < 64; ++k) wreg[k] = W[k * C + lane];
    float bl = b[lane];
    int wv = (blockIdx.x * 256 + tid) >> 6;
    int nW = gridDim.x * 4;
    for (int row = wv; row < NC; row += nW) {
        float* ar = h + (size_t)row * C;
        float acc = bl;
        #pragma unroll
        for (int kk = 0; kk < 16; ++kk) {
            float4 a4 = *(const float4*)(ar + 4 * kk);
            acc = fmaf(a4.x, wreg[4 * kk + 0], acc);
            acc = fmaf(a4.y, wreg[4 * kk + 1], acc);
            acc = fmaf(a4.z, wreg[4 * kk + 2], acc);
            acc = fmaf(a4.w, wreg[4 * kk + 3], acc);
        }
        ar[lane] = acc;
    }
}

__global__ __launch_bounds__(256) void k_inv(
    const int* __restrict__ fwd, int* __restrict__ inv)
{
    int i = blockIdx.x * 256 + threadIdx.x;
    if (i < NC) inv[fwd[i]] = i;
}

__global__ __launch_bounds__(256) void k_gather_fine(
    const float* __restrict__ h, const int2* __restrict__ rec,
    const int* __restrict__ startF, const int* __restrict__ inv,
    float* __restrict__ out)
{
    int tid = threadIdx.x;
    int lane = tid & 63;
    int q = lane >> 4;
    int c4 = (lane & 15) << 2;
    int wv = (blockIdx.x * 256 + tid) >> 6;
    int nW = gridDim.x * 4;
    for (int m = wv; m < NF; m += nW) {
        int iv = inv[m];
        if (iv >= 0) {          // injection: copy h row, skip edges
            if (q == 0) {
                float4 v = *(const float4*)(h + (size_t)iv * C + c4);
                *(float4*)(out + (size_t)m * C + c4) = v;
            }
            continue;
        }
        int s = startF[m], e = startF[m + 1];
        float ax = 0.f, ay = 0.f, az = 0.f, aw = 0.f;
        for (int j = s + 2 * q; j < e; j += 8) {
            int2 r0 = rec[j];
            int j1 = j + 1;
            int2 r1 = (j1 < e) ? rec[j1] : make_int2(0, 0);
            float4 v0 = *(const float4*)(h + (size_t)r0.x * C + c4);
            float w0 = __int_as_float(r0.y);
            ax = fmaf(w0, v0.x, ax); ay = fmaf(w0, v0.y, ay);
            az = fmaf(w0, v0.z, az); aw = fmaf(w0, v0.w, aw);
            if (j1 < e) {
                float4 v1 = *(const float4*)(h + (size_t)r1.x * C + c4);
                float w1 = __int_as_float(r1.y);
                ax = fmaf(w1, v1.x, ax); ay = fmaf(w1, v1.y, ay);
                az = fmaf(w1, v1.z, az); aw = fmaf(w1, v1.w, aw);
            }
        }
        ax += __shfl_xor(ax, 16); ay += __shfl_xor(ay, 16);
        az += __shfl_xor(az, 16); aw += __shfl_xor(aw, 16);
        ax += __shfl_xor(ax, 32); ay += __shfl_xor(ay, 32);
        az += __shfl_xor(az, 32); aw += __shfl_xor(aw, 32);
        if (q == 0)
            *(float4*)(out + (size_t)m * C + c4) = make_float4(ax, ay, az, aw);
    }
}

extern "C" void kernel_launch(void* const* d_in, const int* in_sizes, int n_in,
                              void* d_out, int out_size, void* d_ws, size_t ws_size,
                              hipStream_t stream) {
    const float* x    = (const float*)d_in[0];
    const float* W    = (const float*)d_in[1];
    const float* b    = (const float*)d_in[2];
    const int*   ei   = (const int*)d_in[3];   // [2,E]: src = ei, dst = ei+NE
    const float* ea   = (const float*)d_in[4];
    const int*   psrc = (const int*)d_in[5];
    const int*   pdst = (const int*)d_in[6];
    const float* pw   = (const float*)d_in[7];
    const int*   fwd  = (const int*)d_in[8];
    float* out = (float*)d_out;

    // Workspace (~55.3 MB):
    //  [A: 25.6MB  h  ALIASES  (bsw 12.8MB | bdst 6.4MB)]  -- buckets dead
    //      before gather_coarse writes h
    //  [rec 25.6MB][start 2MB][cnt 2MB (=inv)][bktCnt|bases|curs|chunks|choff]
    char* p = (char*)d_ws;
    float* h    = (float*)p;
    int2*  bsw  = (int2*)p;
    int*   bdst = (int*)(p + (size_t)NE * sizeof(int2));
    p += (size_t)NC * C * sizeof(float);                       // 25.6 MB
    int2* rec   = (int2*)p;  p += (size_t)(2 * NE) * sizeof(int2);   // 25.6 MB
    int* start  = (int*)p;   p += (size_t)(NT + 1) * sizeof(int);
    int* cnt    = (int*)p;   p += (size_t)NT * sizeof(int);
    int* inv    = cnt;                       // reused after places retire
    int* bktCnt = (int*)p;   p += 32 * sizeof(int);
    int* baseC  = (int*)p;   p += 17 * sizeof(int);
    int* baseF  = (int*)p;   p += 17 * sizeof(int);
    int* curC   = (int*)p;   p += 16 * sizeof(int);
    int* curF   = (int*)p;   p += 16 * sizeof(int);
    int* chunks = (int*)p;   p += 512 * sizeof(int);
    int* choff  = (int*)p;

    const int GS = 2048;
    const int nTiles = (NE + 2047) / 2048;        // 782
    const int nChC = (NC + 1023) / 1024;          // 98
    const int nChF = (NF + 1023) / 1024;          // 391

    // zero cnt + bktCnt in one shot (adjacent)
    hipMemsetAsync(cnt, 0, (size_t)(NT + 32) * sizeof(int), stream);

    // bucket sizes for both phases, then bases/cursors
    k_bktcnt<<<GS, 256, 0, stream>>>(ei + NE, pdst, bktCnt);
    k_bktscan<<<1, 64, 0, stream>>>(bktCnt, baseC, baseF, curC, curF);

    // ---- coarse phase: partition -> hist -> scan -> place ----
    k_partition<6250><<<nTiles, 256, 0, stream>>>(ei + NE, ei, ea, curC, bdst, bsw);
    k_hist_bkt<<<GS, 256, 0, stream>>>(bdst, baseC, cnt, 0);
    k_chunk_sum<<<nChC, 256, 0, stream>>>(cnt, NC, chunks);
    k_scan_chunks<<<1, 512, 0, stream>>>(chunks, choff, nChC);
    k_scan_final<<<nChC, 256, 0, stream>>>(cnt, choff, start, NC, NE, 0);
    k_copy<<<(NC + 255) / 256, 256, 0, stream>>>(start, cnt, NC);
    k_place_bkt<<<GS, 256, 0, stream>>>(bdst, bsw, baseC, 0, cnt, rec);

    // ---- fine phase (reuses bucket buffer; coarse place already done) ----
    k_partition<25000><<<nTiles, 256, 0, stream>>>(pdst, psrc, pw, curF, bdst, bsw);
    k_hist_bkt<<<GS, 256, 0, stream>>>(bdst, baseF, cnt, NC);
    k_chunk_sum<<<nChF, 256, 0, stream>>>(cnt + NC, NF, chunks);
    k_scan_chunks<<<1, 512, 0, stream>>>(chunks, choff, nChF);
    k_scan_final<<<nChF, 256, 0, stream>>>(cnt + NC, choff, start + NC, NF, NE, NE);
    k_copy<<<(NF + 255) / 256, 256, 0, stream>>>(start + NC, cnt + NC, NF);
    k_place_bkt<<<GS, 256, 0, stream>>>(bdst, bsw, baseF, NC, cnt, rec);

    // inv map (cursor buffer is dead now)
    hipMemsetAsync(inv, 0xFF, (size_t)NF * sizeof(int), stream);
    k_inv<<<(NC + 255) / 256, 256, 0, stream>>>(fwd, inv);

    // Stage 1: agg = scatter(x) via CSR gather, then in-place GEMM -> h
    k_gather_coarse<<<GS, 256, 0, stream>>>(x, rec, start, h);
    k_gemm_ip<<<GS, 256, 0, stream>>>(h, W, b);

    // Stage 2: fine gather + injection -> out
    k_gather_fine<<<GS, 256, 0, stream>>>(h, rec, start + NC, inv, out);
}

// Round 2
// 589.833 us; speedup vs baseline: 1.2367x; 1.2367x over previous
//
#include <hip/hip_runtime.h>

#define NC 100000
#define NF 400000
#define NE 1600000
#define NT (NC + NF)            // 500000 combined nodes
#define C  64

// ============================================================================
// CSR build v3: no global-atomic hist/place, no 500k-wide scan.
//  k_cnt       : one read of both dst lists -> 256 coarse + 1024 fine
//                sub-range counts (sub-range = 391 dst nodes), LDS-staged.
//  k_subscan   : tiny scans -> sub bases (= global CSR bases, since buckets
//                and subs are dst-contiguous) + bucket cursors.
//  k_partition : 16-way (coarse) / 64-way (fine) dst-range split, 4096-edge
//                tiles -> coalesced 0.75-3KB runs per bucket per block.
//  k_sort      : ONE BLOCK PER SUB-RANGE. Re-scans its bucket's dst array
//                (L2/MALL-hot, 16x re-read of small data), collects its
//                ~6250 (coarse) / ~1560 (fine) edges into LDS, local
//                counting sort (LDS hist + LDS scan), writes rec + start
//                directly. All writes to a rec line come from one block ->
//                one XCD -> lines complete in L2, written back once.
// Gathers / GEMM unchanged.
// ============================================================================

#define SUBDIV 391              // dst nodes per sub-range (16*391 >= 6250)
#define BDIV   6250             // dst nodes per bucket (coarse:16, fine:64 bkts)

__global__ __launch_bounds__(256) void k_cnt(
    const int* __restrict__ cd, const int* __restrict__ pd,
    int* __restrict__ subCntC, int* __restrict__ subCntF)
{
    __shared__ int lc[256];
    __shared__ int lf[1024];
    int tid = threadIdx.x;
    lc[tid] = 0;
    for (int i = tid; i < 1024; i += 256) lf[i] = 0;
    __syncthreads();
    int stride = gridDim.x * 256;
    for (int e = blockIdx.x * 256 + tid; e < NE; e += stride) {
        int d = cd[e];
        int b = d / BDIV;
        atomicAdd(&lc[b * 16 + (d - b * BDIV) / SUBDIV], 1);
        int f = pd[e];
        int bf = f / BDIV;
        atomicAdd(&lf[bf * 16 + (f - bf * BDIV) / SUBDIV], 1);
    }
    __syncthreads();
    atomicAdd(&subCntC[tid], lc[tid]);
    for (int i = tid; i < 1024; i += 256) atomicAdd(&subCntF[i], lf[i]);
}

__global__ __launch_bounds__(1024) void k_subscan(
    const int* __restrict__ subCntC, const int* __restrict__ subCntF,
    int* __restrict__ subBaseC, int* __restrict__ subBaseF,
    int* __restrict__ curC, int* __restrict__ curF, int* __restrict__ start)
{
    __shared__ int sd[1024];
    int t = threadIdx.x;
    // ---- coarse: scan 256 ----
    int v = (t < 256) ? subCntC[t] : 0;
    sd[t] = v; __syncthreads();
    for (int off = 1; off < 1024; off <<= 1) {
        int x = sd[t];
        if (t >= off) x += sd[t - off];
        __syncthreads(); sd[t] = x; __syncthreads();
    }
    if (t < 256) subBaseC[t] = sd[t] - v;       // exclusive
    if (t == 255) subBaseC[256] = sd[t];        // sentinel = NE
    __syncthreads();
    // ---- fine: scan 1024 ----
    int vf = subCntF[t];
    sd[t] = vf; __syncthreads();
    for (int off = 1; off < 1024; off <<= 1) {
        int x = sd[t];
        if (t >= off) x += sd[t - off];
        __syncthreads(); sd[t] = x; __syncthreads();
    }
    subBaseF[t] = sd[t] - vf;
    if (t == 1023) subBaseF[1024] = sd[t];      // sentinel = NE
    __syncthreads();
    if (t < 16) curC[t] = subBaseC[t * 16];
    if (t < 64) curF[t] = subBaseF[t * 16];
    if (t == 0) start[NT] = 2 * NE;
}

// 4096-edge tiles: 16 regs/thread; bucket runs 256 edges (coarse) / 64 (fine)
// -> coalesced multi-line writes; only NBKT global cursor atomics per block.
template<int NBKT>
__global__ __launch_bounds__(256) void k_partition(
    const int* __restrict__ dst, const int* __restrict__ src,
    const float* __restrict__ w, int* __restrict__ bktCur,
    int* __restrict__ bdst, int2* __restrict__ bsw)
{
    __shared__ int lcnt[NBKT];
    int tid = threadIdx.x;
    int e0 = blockIdx.x * 4096;
    for (int i = tid; i < NBKT; i += 256) lcnt[i] = 0;
    __syncthreads();
    int rd[16]; int rs[16]; float rw[16];
    #pragma unroll
    for (int i = 0; i < 16; ++i) {
        int e = e0 + i * 256 + tid;
        if (e < NE) {
            rd[i] = dst[e]; rs[i] = src[e]; rw[i] = w[e];
            atomicAdd(&lcnt[rd[i] / BDIV], 1);
        } else rd[i] = -1;
    }
    __syncthreads();
    for (int i = tid; i < NBKT; i += 256) lcnt[i] = atomicAdd(&bktCur[i], lcnt[i]);
    __syncthreads();
    #pragma unroll
    for (int i = 0; i < 16; ++i) {
        if (rd[i] >= 0) {
            int b = rd[i] / BDIV;
            int p = atomicAdd(&lcnt[b], 1);
            bdst[p] = rd[i];
            bsw[p]  = make_int2(rs[i], __float_as_int(rw[i]));
        }
    }
}

// One block per sub-range. blockIdx = b*16 + s.
template<int CAP>
__global__ __launch_bounds__(512) void k_sort(
    const int* __restrict__ bdst, const int2* __restrict__ bsw,
    const int* __restrict__ subBase, int edgeBase, int nodeBase,
    int2* __restrict__ rec, int* __restrict__ start)
{
    constexpr int NTHR = 512;
    __shared__ unsigned short dstl[CAP];
    __shared__ int2 swl[CAP];
    __shared__ int cnt[SUBDIV + 1];
    __shared__ int scn[NTHR];
    __shared__ int nloc;
    int tid  = threadIdx.x;
    int blk  = blockIdx.x;
    int b    = blk >> 4, s = blk & 15;
    int nodeLo = b * BDIV + s * SUBDIV;
    int nodeHi = min(b * BDIV + (s + 1) * SUBDIV, (b + 1) * BDIV);
    int nNodes = nodeHi - nodeLo;               // 391, or 385 for s==15
    int gbase  = edgeBase + subBase[blk];
    if (tid == 0) nloc = 0;
    for (int i = tid; i < SUBDIV + 1; i += NTHR) cnt[i] = 0;
    __syncthreads();

    // ---- collect: re-scan bucket's dst array, keep edges in my sub-range ----
    int bklo = subBase[b * 16], bkhi = subBase[b * 16 + 16];
    int lane = tid & 63;
    for (int i0 = bklo + tid; i0 < bkhi; i0 += 4 * NTHR) {
        int dv[4];
        #pragma unroll
        for (int k = 0; k < 4; ++k) {
            int i = i0 + k * NTHR;
            dv[k] = (i < bkhi) ? bdst[i] : -1;
        }
        #pragma unroll
        for (int k = 0; k < 4; ++k) {
            int i  = i0 + k * NTHR;
            int dl = dv[k] - nodeLo;
            bool m = (unsigned)dl < (unsigned)nNodes;
            unsigned long long mask = __ballot(m);
            int cw = __popcll(mask);
            int wbase = 0;
            if (lane == 0 && cw) wbase = atomicAdd(&nloc, cw);
            wbase = __shfl(wbase, 0);
            if (m) {
                int pos = wbase + __popcll(mask & ((1ull << lane) - 1));
                if (pos < CAP) {
                    dstl[pos] = (unsigned short)dl;
                    swl[pos]  = bsw[i];
                    atomicAdd(&cnt[dl], 1);
                }
            }
        }
    }
    __syncthreads();

    // ---- local exclusive scan of 391 node counts ----
    int v = (tid < SUBDIV) ? cnt[tid] : 0;
    scn[tid] = v; __syncthreads();
    for (int off = 1; off < NTHR; off <<= 1) {
        int x = scn[tid];
        if (tid >= off) x += scn[tid - off];
        __syncthreads(); scn[tid] = x; __syncthreads();
    }
    int excl = scn[tid] - v;
    if (tid < nNodes) start[nodeBase + nodeLo + tid] = gbase + excl;
    if (tid < SUBDIV) cnt[tid] = excl;          // reuse as cursor
    __syncthreads();

    // ---- place: scattered 8B writes confined to this block's <=57KB region ----
    int n = min(nloc, CAP);
    for (int i = tid; i < n; i += NTHR) {
        int dl = dstl[i];
        int p  = atomicAdd(&cnt[dl], 1);
        rec[gbase + p] = swl[i];
    }
}

// ---------------- Gathers / GEMM (unchanged, proven) ----------------
__global__ __launch_bounds__(256) void k_gather_coarse(
    const float* __restrict__ x, const int2* __restrict__ rec,
    const int* __restrict__ start, float* __restrict__ agg)
{
    int tid = threadIdx.x;
    int lane = tid & 63;
    int q = lane >> 4;
    int c4 = (lane & 15) << 2;
    int wv = (blockIdx.x * 256 + tid) >> 6;
    int nW = gridDim.x * 4;
    for (int n = wv; n < NC; n += nW) {
        int s = start[n], e = start[n + 1];
        float ax = 0.f, ay = 0.f, az = 0.f, aw = 0.f;
        for (int j = s + 2 * q; j < e; j += 8) {
            int2 r0 = rec[j];
            int j1 = j + 1;
            int2 r1 = (j1 < e) ? rec[j1] : make_int2(0, 0);
            float4 v0 = *(const float4*)(x + (size_t)r0.x * C + c4);
            float w0 = __int_as_float(r0.y);
            ax = fmaf(w0, v0.x, ax); ay = fmaf(w0, v0.y, ay);
            az = fmaf(w0, v0.z, az); aw = fmaf(w0, v0.w, aw);
            if (j1 < e) {
                float4 v1 = *(const float4*)(x + (size_t)r1.x * C + c4);
                float w1 = __int_as_float(r1.y);
                ax = fmaf(w1, v1.x, ax); ay = fmaf(w1, v1.y, ay);
                az = fmaf(w1, v1.z, az); aw = fmaf(w1, v1.w, aw);
            }
        }
        ax += __shfl_xor(ax, 16); ay += __shfl_xor(ay, 16);
        az += __shfl_xor(az, 16); aw += __shfl_xor(aw, 16);
        ax += __shfl_xor(ax, 32); ay += __shfl_xor(ay, 32);
        az += __shfl_xor(az, 32); aw += __shfl_xor(aw, 32);
        if (q == 0)
            *(float4*)(agg + (size_t)n * C + c4) = make_float4(ax, ay, az, aw);
    }
}

__global__ __launch_bounds__(256) void k_gemm_ip(
    float* __restrict__ h, const float* __restrict__ W, const float* __restrict__ b)
{
    int tid = threadIdx.x;
    int lane = tid & 63;
    float wreg[64];
    #pragma unroll
    for (int k = 0; k < 64; ++k) wreg[k] = W[k * C + lane];
    float bl = b[lane];
    int wv = (blockIdx.x * 256 + tid) >> 6;
    int nW = gridDim.x * 4;
    for (int row = wv; row < NC; row += nW) {
        float* ar = h + (size_t)row * C;
        float acc = bl;
        #pragma unroll
        for (int kk = 0; kk < 16; ++kk) {
            float4 a4 = *(const float4*)(ar + 4 * kk);
            acc = fmaf(a4.x, wreg[4 * kk + 0], acc);
            acc = fmaf(a4.y, wreg[4 * kk + 1], acc);
            acc = fmaf(a4.z, wreg[4 * kk + 2], acc);
            acc = fmaf(a4.w, wreg[4 * kk + 3], acc);
        }
        ar[lane] = acc;
    }
}

__global__ __launch_bounds__(256) void k_inv(
    const int* __restrict__ fwd, int* __restrict__ inv)
{
    int i = blockIdx.x * 256 + threadIdx.x;
    if (i < NC) inv[fwd[i]] = i;
}

__global__ __launch_bounds__(256) void k_gather_fine(
    const float* __restrict__ h, const int2* __restrict__ rec,
    const int* __restrict__ startF, const int* __restrict__ inv,
    float* __restrict__ out)
{
    int tid = threadIdx.x;
    int lane = tid & 63;
    int q = lane >> 4;
    int c4 = (lane & 15) << 2;
    int wv = (blockIdx.x * 256 + tid) >> 6;
    int nW = gridDim.x * 4;
    for (int m = wv; m < NF; m += nW) {
        int iv = inv[m];
        if (iv >= 0) {          // injection: copy h row, skip edges
            if (q == 0) {
                float4 v = *(const float4*)(h + (size_t)iv * C + c4);
                *(float4*)(out + (size_t)m * C + c4) = v;
            }
            continue;
        }
        int s = startF[m], e = startF[m + 1];
        float ax = 0.f, ay = 0.f, az = 0.f, aw = 0.f;
        for (int j = s + 2 * q; j < e; j += 8) {
            int2 r0 = rec[j];
            int j1 = j + 1;
            int2 r1 = (j1 < e) ? rec[j1] : make_int2(0, 0);
            float4 v0 = *(const float4*)(h + (size_t)r0.x * C + c4);
            float w0 = __int_as_float(r0.y);
            ax = fmaf(w0, v0.x, ax); ay = fmaf(w0, v0.y, ay);
            az = fmaf(w0, v0.z, az); aw = fmaf(w0, v0.w, aw);
            if (j1 < e) {
                float4 v1 = *(const float4*)(h + (size_t)r1.x * C + c4);
                float w1 = __int_as_float(r1.y);
                ax = fmaf(w1, v1.x, ax); ay = fmaf(w1, v1.y, ay);
                az = fmaf(w1, v1.z, az); aw = fmaf(w1, v1.w, aw);
            }
        }
        ax += __shfl_xor(ax, 16); ay += __shfl_xor(ay, 16);
        az += __shfl_xor(az, 16); aw += __shfl_xor(aw, 16);
        ax += __shfl_xor(ax, 32); ay += __shfl_xor(ay, 32);
        az += __shfl_xor(az, 32); aw += __shfl_xor(aw, 32);
        if (q == 0)
            *(float4*)(out + (size_t)m * C + c4) = make_float4(ax, ay, az, aw);
    }
}

extern "C" void kernel_launch(void* const* d_in, const int* in_sizes, int n_in,
                              void* d_out, int out_size, void* d_ws, size_t ws_size,
                              hipStream_t stream) {
    const float* x    = (const float*)d_in[0];
    const float* W    = (const float*)d_in[1];
    const float* b    = (const float*)d_in[2];
    const int*   ei   = (const int*)d_in[3];   // [2,E]: src = ei, dst = ei+NE
    const float* ea   = (const float*)d_in[4];
    const int*   psrc = (const int*)d_in[5];
    const int*   pdst = (const int*)d_in[6];
    const float* pw   = (const float*)d_in[7];
    const int*   fwd  = (const int*)d_in[8];
    float* out = (float*)d_out;

    // Workspace (~55 MB):
    //  [A: 25.6MB  h  ALIASES  (bsw 12.8MB | bdst 6.4MB)] -- buckets dead
    //      before gather_coarse writes h
    //  [rec 25.6MB][start 2MB][inv 1.6MB][subCntC|subCntF|bases|curs]
    char* p = (char*)d_ws;
    float* h    = (float*)p;
    int2*  bsw  = (int2*)p;
    int*   bdst = (int*)(p + (size_t)NE * sizeof(int2));
    p += (size_t)NC * C * sizeof(float);                             // 25.6 MB
    int2* rec     = (int2*)p;  p += (size_t)(2 * NE) * sizeof(int2); // 25.6 MB
    int* start    = (int*)p;   p += (size_t)(NT + 1) * sizeof(int);
    int* inv      = (int*)p;   p += (size_t)NF * sizeof(int);
    int* subCntC  = (int*)p;   p += 256 * sizeof(int);
    int* subCntF  = (int*)p;   p += 1024 * sizeof(int);
    int* subBaseC = (int*)p;   p += 257 * sizeof(int);
    int* subBaseF = (int*)p;   p += 1025 * sizeof(int);
    int* curC     = (int*)p;   p += 16 * sizeof(int);
    int* curF     = (int*)p;   p += 64 * sizeof(int);

    const int GS = 2048;
    const int nTiles = (NE + 4095) / 4096;        // 391

    // zero sub counters (contiguous subCntC+subCntF)
    hipMemsetAsync(subCntC, 0, (256 + 1024) * sizeof(int), stream);

    // counts -> bases/cursors
    k_cnt<<<256, 256, 0, stream>>>(ei + NE, pdst, subCntC, subCntF);
    k_subscan<<<1, 1024, 0, stream>>>(subCntC, subCntF, subBaseC, subBaseF,
                                      curC, curF, start);

    // ---- coarse: partition 16-way -> per-sub LDS sort ----
    k_partition<16><<<nTiles, 256, 0, stream>>>(ei + NE, ei, ea, curC, bdst, bsw);
    k_sort<7168><<<256, 512, 0, stream>>>(bdst, bsw, subBaseC, 0, 0, rec, start);

    // ---- fine: partition 64-way -> per-sub LDS sort (reuses buckets) ----
    k_partition<64><<<nTiles, 256, 0, stream>>>(pdst, psrc, pw, curF, bdst, bsw);
    k_sort<2048><<<1024, 512, 0, stream>>>(bdst, bsw, subBaseF, NE, NC, rec, start);

    // inv map
    hipMemsetAsync(inv, 0xFF, (size_t)NF * sizeof(int), stream);
    k_inv<<<(NC + 255) / 256, 256, 0, stream>>>(fwd, inv);

    // Stage 1: agg = scatter(x) via CSR gather, then in-place GEMM -> h
    k_gather_coarse<<<GS, 256, 0, stream>>>(x, rec, start, h);
    k_gemm_ip<<<GS, 256, 0, stream>>>(h, W, b);

    // Stage 2: fine gather + injection -> out
    k_gather_fine<<<GS, 256, 0, stream>>>(h, rec, start + NC, inv, out);
}

// Round 3
// 504.805 us; speedup vs baseline: 1.4450x; 1.1684x over previous
//
#include <hip/hip_runtime.h>

#define NC 100000
#define NF 400000
#define NE 1600000
#define NT (NC + NF)            // 500000 combined nodes
#define C  64

// ============================================================================
// CSR build v4: bucket == sub-range (zero re-scan).
//  k_cnt       : one read of both dst lists -> 256 coarse + 1024 fine
//                sub-range counts (sub-range = 391 dst nodes).
//  k_subscan   : tiny scans -> sub bases (= global CSR bases) + cursors.
//  k_partition : 256-way (coarse) / 1024-way (fine) dst-range split into
//                contiguous per-sub bucket arrays. Runs per tile are short
//                (~16 / ~4 edges) -> some write amplification, but this buys
//                zero-redundancy sorts.
//  k_sort      : ONE BLOCK PER SUB-RANGE, slice is exactly
//                [subBase[blk], subBase[blk+1]) -- straight coalesced copy
//                into LDS (no ballot/filter), LDS hist (391 counters) +
//                LDS scan, write start + rec directly. All writes to a rec
//                line come from one block -> one XCD -> no line bounce.
// Gathers / GEMM unchanged.
// ============================================================================

#define SUBDIV 391              // dst nodes per sub-range
#define NSUBC  256              // 256*391 >= 100000
#define NSUBF  1024             // 1024*391 >= 400000

__global__ __launch_bounds__(256) void k_cnt(
    const int* __restrict__ cd, const int* __restrict__ pd,
    int* __restrict__ subCntC, int* __restrict__ subCntF)
{
    __shared__ int lc[NSUBC];
    __shared__ int lf[NSUBF];
    int tid = threadIdx.x;
    lc[tid] = 0;
    for (int i = tid; i < NSUBF; i += 256) lf[i] = 0;
    __syncthreads();
    int stride = gridDim.x * 256;
    for (int e = blockIdx.x * 256 + tid; e < NE; e += stride) {
        atomicAdd(&lc[cd[e] / SUBDIV], 1);
        atomicAdd(&lf[pd[e] / SUBDIV], 1);
    }
    __syncthreads();
    atomicAdd(&subCntC[tid], lc[tid]);
    for (int i = tid; i < NSUBF; i += 256) atomicAdd(&subCntF[i], lf[i]);
}

__global__ __launch_bounds__(1024) void k_subscan(
    const int* __restrict__ subCntC, const int* __restrict__ subCntF,
    int* __restrict__ subBaseC, int* __restrict__ subBaseF,
    int* __restrict__ curC, int* __restrict__ curF, int* __restrict__ start)
{
    __shared__ int sd[1024];
    int t = threadIdx.x;
    // ---- coarse: scan 256 ----
    int v = (t < NSUBC) ? subCntC[t] : 0;
    sd[t] = v; __syncthreads();
    for (int off = 1; off < 1024; off <<= 1) {
        int x = sd[t];
        if (t >= off) x += sd[t - off];
        __syncthreads(); sd[t] = x; __syncthreads();
    }
    if (t < NSUBC) { subBaseC[t] = sd[t] - v; curC[t] = sd[t] - v; }
    if (t == NSUBC - 1) subBaseC[NSUBC] = sd[t];     // = NE
    __syncthreads();
    // ---- fine: scan 1024 ----
    int vf = subCntF[t];
    sd[t] = vf; __syncthreads();
    for (int off = 1; off < 1024; off <<= 1) {
        int x = sd[t];
        if (t >= off) x += sd[t - off];
        __syncthreads(); sd[t] = x; __syncthreads();
    }
    subBaseF[t] = sd[t] - vf;
    curF[t] = sd[t] - vf;
    if (t == NSUBF - 1) subBaseF[NSUBF] = sd[t];     // = NE
    if (t == 0) start[NT] = 2 * NE;
}

// 4096-edge tiles; NBKT global cursor atomics per block; per-tile bucket
// runs are contiguous -> mostly coalesced writes.
template<int NBKT>
__global__ __launch_bounds__(256) void k_partition(
    const int* __restrict__ dst, const int* __restrict__ src,
    const float* __restrict__ w, int* __restrict__ bktCur,
    int* __restrict__ bdst, int2* __restrict__ bsw)
{
    __shared__ int lcnt[NBKT];
    int tid = threadIdx.x;
    int e0 = blockIdx.x * 4096;
    for (int i = tid; i < NBKT; i += 256) lcnt[i] = 0;
    __syncthreads();
    int rd[16]; int rs[16]; float rw[16];
    #pragma unroll
    for (int i = 0; i < 16; ++i) {
        int e = e0 + i * 256 + tid;
        if (e < NE) {
            rd[i] = dst[e]; rs[i] = src[e]; rw[i] = w[e];
            atomicAdd(&lcnt[rd[i] / SUBDIV], 1);
        } else rd[i] = -1;
    }
    __syncthreads();
    for (int i = tid; i < NBKT; i += 256) lcnt[i] = atomicAdd(&bktCur[i], lcnt[i]);
    __syncthreads();
    #pragma unroll
    for (int i = 0; i < 16; ++i) {
        if (rd[i] >= 0) {
            int b = rd[i] / SUBDIV;
            int p = atomicAdd(&lcnt[b], 1);
            bdst[p] = rd[i];
            bsw[p]  = make_int2(rs[i], __float_as_int(rw[i]));
        }
    }
}

// One block per sub-range; slice [subBase[blk], subBase[blk+1]) is mine.
template<int CAP>
__global__ __launch_bounds__(512) void k_sort(
    const int* __restrict__ bdst, const int2* __restrict__ bsw,
    const int* __restrict__ subBase, int edgeBase, int nodeBase, int nNodesTot,
    int2* __restrict__ rec, int* __restrict__ start)
{
    constexpr int NTHR = 512;
    __shared__ unsigned short dstl[CAP];
    __shared__ int2 swl[CAP];
    __shared__ int cnt[SUBDIV + 1];
    __shared__ int scn[NTHR];
    int tid = threadIdx.x;
    int blk = blockIdx.x;
    int nodeLo = blk * SUBDIV;
    int nNodes = min(SUBDIV, nNodesTot - nodeLo);
    int lo = subBase[blk], hi = subBase[blk + 1];
    int n = min(hi - lo, CAP);
    int gbase = edgeBase + lo;
    for (int i = tid; i < SUBDIV + 1; i += NTHR) cnt[i] = 0;
    __syncthreads();

    // ---- collect: straight coalesced copy of my slice ----
    for (int i = tid; i < n; i += NTHR) {
        int dl = bdst[lo + i] - nodeLo;
        dstl[i] = (unsigned short)dl;
        swl[i]  = bsw[lo + i];
        atomicAdd(&cnt[dl], 1);
    }
    __syncthreads();

    // ---- local exclusive scan of node counts ----
    int v = (tid < SUBDIV) ? cnt[tid] : 0;
    scn[tid] = v; __syncthreads();
    for (int off = 1; off < NTHR; off <<= 1) {
        int x = scn[tid];
        if (tid >= off) x += scn[tid - off];
        __syncthreads(); scn[tid] = x; __syncthreads();
    }
    int excl = scn[tid] - v;
    if (tid < nNodes) start[nodeBase + nodeLo + tid] = gbase + excl;
    if (tid < SUBDIV) cnt[tid] = excl;          // reuse as cursor
    __syncthreads();

    // ---- place: scattered 8B writes confined to this block's region ----
    for (int i = tid; i < n; i += NTHR) {
        int dl = dstl[i];
        int p  = atomicAdd(&cnt[dl], 1);
        rec[gbase + p] = swl[i];
    }
}

// ---------------- Gathers / GEMM (unchanged, proven) ----------------
__global__ __launch_bounds__(256) void k_gather_coarse(
    const float* __restrict__ x, const int2* __restrict__ rec,
    const int* __restrict__ start, float* __restrict__ agg)
{
    int tid = threadIdx.x;
    int lane = tid & 63;
    int q = lane >> 4;
    int c4 = (lane & 15) << 2;
    int wv = (blockIdx.x * 256 + tid) >> 6;
    int nW = gridDim.x * 4;
    for (int n = wv; n < NC; n += nW) {
        int s = start[n], e = start[n + 1];
        float ax = 0.f, ay = 0.f, az = 0.f, aw = 0.f;
        for (int j = s + 2 * q; j < e; j += 8) {
            int2 r0 = rec[j];
            int j1 = j + 1;
            int2 r1 = (j1 < e) ? rec[j1] : make_int2(0, 0);
            float4 v0 = *(const float4*)(x + (size_t)r0.x * C + c4);
            float w0 = __int_as_float(r0.y);
            ax = fmaf(w0, v0.x, ax); ay = fmaf(w0, v0.y, ay);
            az = fmaf(w0, v0.z, az); aw = fmaf(w0, v0.w, aw);
            if (j1 < e) {
                float4 v1 = *(const float4*)(x + (size_t)r1.x * C + c4);
                float w1 = __int_as_float(r1.y);
                ax = fmaf(w1, v1.x, ax); ay = fmaf(w1, v1.y, ay);
                az = fmaf(w1, v1.z, az); aw = fmaf(w1, v1.w, aw);
            }
        }
        ax += __shfl_xor(ax, 16); ay += __shfl_xor(ay, 16);
        az += __shfl_xor(az, 16); aw += __shfl_xor(aw, 16);
        ax += __shfl_xor(ax, 32); ay += __shfl_xor(ay, 32);
        az += __shfl_xor(az, 32); aw += __shfl_xor(aw, 32);
        if (q == 0)
            *(float4*)(agg + (size_t)n * C + c4) = make_float4(ax, ay, az, aw);
    }
}

__global__ __launch_bounds__(256) void k_gemm_ip(
    float* __restrict__ h, const float* __restrict__ W, const float* __restrict__ b)
{
    int tid = threadIdx.x;
    int lane = tid & 63;
    float wreg[64];
    #pragma unroll
    for (int k = 0; k < 64; ++k) wreg[k] = W[k * C + lane];
    float bl = b[lane];
    int wv = (blockIdx.x * 256 + tid) >> 6;
    int nW = gridDim.x * 4;
    for (int row = wv; row < NC; row += nW) {
        float* ar = h + (size_t)row * C;
        float acc = bl;
        #pragma unroll
        for (int kk = 0; kk < 16; ++kk) {
            float4 a4 = *(const float4*)(ar + 4 * kk);
            acc = fmaf(a4.x, wreg[4 * kk + 0], acc);
            acc = fmaf(a4.y, wreg[4 * kk + 1], acc);
            acc = fmaf(a4.z, wreg[4 * kk + 2], acc);
            acc = fmaf(a4.w, wreg[4 * kk + 3], acc);
        }
        ar[lane] = acc;
    }
}

__global__ __launch_bounds__(256) void k_inv(
    const int* __restrict__ fwd, int* __restrict__ inv)
{
    int i = blockIdx.x * 256 + threadIdx.x;
    if (i < NC) inv[fwd[i]] = i;
}

__global__ __launch_bounds__(256) void k_gather_fine(
    const float* __restrict__ h, const int2* __restrict__ rec,
    const int* __restrict__ startF, const int* __restrict__ inv,
    float* __restrict__ out)
{
    int tid = threadIdx.x;
    int lane = tid & 63;
    int q = lane >> 4;
    int c4 = (lane & 15) << 2;
    int wv = (blockIdx.x * 256 + tid) >> 6;
    int nW = gridDim.x * 4;
    for (int m = wv; m < NF; m += nW) {
        int iv = inv[m];
        if (iv >= 0) {          // injection: copy h row, skip edges
            if (q == 0) {
                float4 v = *(const float4*)(h + (size_t)iv * C + c4);
                *(float4*)(out + (size_t)m * C + c4) = v;
            }
            continue;
        }
        int s = startF[m], e = startF[m + 1];
        float ax = 0.f, ay = 0.f, az = 0.f, aw = 0.f;
        for (int j = s + 2 * q; j < e; j += 8) {
            int2 r0 = rec[j];
            int j1 = j + 1;
            int2 r1 = (j1 < e) ? rec[j1] : make_int2(0, 0);
            float4 v0 = *(const float4*)(h + (size_t)r0.x * C + c4);
            float w0 = __int_as_float(r0.y);
            ax = fmaf(w0, v0.x, ax); ay = fmaf(w0, v0.y, ay);
            az = fmaf(w0, v0.z, az); aw = fmaf(w0, v0.w, aw);
            if (j1 < e) {
                float4 v1 = *(const float4*)(h + (size_t)r1.x * C + c4);
                float w1 = __int_as_float(r1.y);
                ax = fmaf(w1, v1.x, ax); ay = fmaf(w1, v1.y, ay);
                az = fmaf(w1, v1.z, az); aw = fmaf(w1, v1.w, aw);
            }
        }
        ax += __shfl_xor(ax, 16); ay += __shfl_xor(ay, 16);
        az += __shfl_xor(az, 16); aw += __shfl_xor(aw, 16);
        ax += __shfl_xor(ax, 32); ay += __shfl_xor(ay, 32);
        az += __shfl_xor(az, 32); aw += __shfl_xor(aw, 32);
        if (q == 0)
            *(float4*)(out + (size_t)m * C + c4) = make_float4(ax, ay, az, aw);
    }
}

extern "C" void kernel_launch(void* const* d_in, const int* in_sizes, int n_in,
                              void* d_out, int out_size, void* d_ws, size_t ws_size,
                              hipStream_t stream) {
    const float* x    = (const float*)d_in[0];
    const float* W    = (const float*)d_in[1];
    const float* b    = (const float*)d_in[2];
    const int*   ei   = (const int*)d_in[3];   // [2,E]: src = ei, dst = ei+NE
    const float* ea   = (const float*)d_in[4];
    const int*   psrc = (const int*)d_in[5];
    const int*   pdst = (const int*)d_in[6];
    const float* pw   = (const float*)d_in[7];
    const int*   fwd  = (const int*)d_in[8];
    float* out = (float*)d_out;

    // Workspace (~55 MB):
    //  [A: 25.6MB  h  ALIASES  (bsw 12.8MB | bdst 6.4MB)] -- buckets dead
    //      before gather_coarse writes h
    //  [rec 25.6MB][start 2MB][inv 1.6MB][subCnt|subBase|cur]
    char* p = (char*)d_ws;
    float* h    = (float*)p;
    int2*  bsw  = (int2*)p;
    int*   bdst = (int*)(p + (size_t)NE * sizeof(int2));
    p += (size_t)NC * C * sizeof(float);                             // 25.6 MB
    int2* rec     = (int2*)p;  p += (size_t)(2 * NE) * sizeof(int2); // 25.6 MB
    int* start    = (int*)p;   p += (size_t)(NT + 1) * sizeof(int);
    int* inv      = (int*)p;   p += (size_t)NF * sizeof(int);
    int* subCntC  = (int*)p;   p += NSUBC * sizeof(int);
    int* subCntF  = (int*)p;   p += NSUBF * sizeof(int);
    int* subBaseC = (int*)p;   p += (NSUBC + 1) * sizeof(int);
    int* subBaseF = (int*)p;   p += (NSUBF + 1) * sizeof(int);
    int* curC     = (int*)p;   p += NSUBC * sizeof(int);
    int* curF     = (int*)p;   p += NSUBF * sizeof(int);

    const int GS = 2048;
    const int nTiles = (NE + 4095) / 4096;        // 391

    // zero sub counters (contiguous subCntC+subCntF)
    hipMemsetAsync(subCntC, 0, (NSUBC + NSUBF) * sizeof(int), stream);

    // counts -> bases/cursors
    k_cnt<<<256, 256, 0, stream>>>(ei + NE, pdst, subCntC, subCntF);
    k_subscan<<<1, 1024, 0, stream>>>(subCntC, subCntF, subBaseC, subBaseF,
                                      curC, curF, start);

    // ---- coarse: partition 256-way -> per-sub LDS sort (no re-scan) ----
    k_partition<NSUBC><<<nTiles, 256, 0, stream>>>(ei + NE, ei, ea, curC, bdst, bsw);
    k_sort<7168><<<NSUBC, 512, 0, stream>>>(bdst, bsw, subBaseC, 0, 0, NC,
                                            rec, start);

    // ---- fine: partition 1024-way -> per-sub LDS sort (reuses buckets) ----
    k_partition<NSUBF><<<nTiles, 256, 0, stream>>>(pdst, psrc, pw, curF, bdst, bsw);
    k_sort<2048><<<NSUBF, 512, 0, stream>>>(bdst, bsw, subBaseF, NE, NC, NF,
                                            rec, start);

    // inv map
    hipMemsetAsync(inv, 0xFF, (size_t)NF * sizeof(int), stream);
    k_inv<<<(NC + 255) / 256, 256, 0, stream>>>(fwd, inv);

    // Stage 1: agg = scatter(x) via CSR gather, then in-place GEMM -> h
    k_gather_coarse<<<GS, 256, 0, stream>>>(x, rec, start, h);
    k_gemm_ip<<<GS, 256, 0, stream>>>(h, W, b);

    // Stage 2: fine gather + injection -> out
    k_gather_fine<<<GS, 256, 0, stream>>>(h, rec, start + NC, inv, out);
}

// Round 4
// 376.750 us; speedup vs baseline: 1.9361x; 1.3399x over previous
//
#include <hip/hip_runtime.h>

#define NC 100000
#define NF 400000
#define NE 1600000
#define C  64

// ============================================================================
// v5: CSR never materialized in global memory.
//  k_curinit    : bucket cursors <- b*CAPB (fixed-capacity buckets, no
//                 count/scan prepass at all).
//  k_partition  : 512-way dst-range split; record packed to 8B:
//                 {dl<<17 | src, w} (dl = dst - bucket*SUBDIV < 1024,
//                 src < 2^17). Per-tile bucket runs ~8 records = 64B.
//  k_sortgather : ONE BLOCK PER BUCKET (512 blocks, 1024 thr, 2 blocks/CU).
//                 Records -> regs, LDS hist (<=783 counters) + LDS scan,
//                 place into LDS sorted array (32KB), then gather:
//                 one 16-lane quadrant per dst node (64 quadrants — all
//                 lanes busy even at deg~4), quad-unrolled feature-row
//                 loads, coalesced 256B out-row writes. Handles injection
//                 (fine phase) via inv.
//  Deleted vs v4: k_cnt, k_subscan, 2x k_sort, rec (25.6MB w+r),
//  start (w+r). 13 dispatches -> 8.
// ============================================================================

#define NSUB 512                // buckets per phase
#define CAPB 4096               // records per bucket (mean ~3130, +17 sigma)
#define SUBC 196                // dst nodes per coarse bucket (512*196>=100000)
#define SUBF 782                // dst nodes per fine bucket (512*782>=400000)

__global__ __launch_bounds__(1024) void k_curinit(
    int* __restrict__ curC, int* __restrict__ curF)
{
    int t = threadIdx.x;
    if (t < NSUB) { curC[t] = t * CAPB; curF[t] = t * CAPB; }
}

template<int SUBDIV>
__global__ __launch_bounds__(256) void k_partition(
    const int* __restrict__ dst, const int* __restrict__ src,
    const float* __restrict__ w, int* __restrict__ cur, int2* __restrict__ buf)
{
    __shared__ int lcnt[NSUB];
    int tid = threadIdx.x;
    int e0 = blockIdx.x * 4096;
    for (int i = tid; i < NSUB; i += 256) lcnt[i] = 0;
    __syncthreads();
    int rb[16]; int2 rv[16];
    #pragma unroll
    for (int i = 0; i < 16; ++i) {
        int e = e0 + i * 256 + tid;
        if (e < NE) {
            int d  = dst[e];
            int bk = d / SUBDIV;
            rb[i]  = bk;
            rv[i]  = make_int2(((d - bk * SUBDIV) << 17) | src[e],
                               __float_as_int(w[e]));
            atomicAdd(&lcnt[bk], 1);
        } else rb[i] = -1;
    }
    __syncthreads();
    for (int i = tid; i < NSUB; i += 256)
        lcnt[i] = atomicAdd(&cur[i], lcnt[i]);
    __syncthreads();
    #pragma unroll
    for (int i = 0; i < 16; ++i) {
        if (rb[i] >= 0) {
            int p = atomicAdd(&lcnt[rb[i]], 1);
            if (p < (rb[i] + 1) * CAPB) buf[p] = rv[i];   // overflow guard
        }
    }
}

// Block = bucket. LDS sort + direct gather; no global CSR.
template<int SUBDIV, int NTOT, bool FINE>
__global__ __launch_bounds__(1024, 8) void k_sortgather(
    const int2* __restrict__ buf, const int* __restrict__ cur,
    const float* __restrict__ feat,      // x (coarse) or h (fine)
    const int* __restrict__ inv,         // fine only
    float* __restrict__ outp)            // h/agg (coarse) or out (fine)
{
    __shared__ int2 srt[CAPB];           // 32 KB sorted records
    __shared__ int  cnt[SUBDIV];         // per-node cursor/end
    __shared__ int  scn[1024];
    int tid = threadIdx.x;
    int blk = blockIdx.x;
    int nodeLo = blk * SUBDIV;
    int nNodes = min(SUBDIV, NTOT - nodeLo);
    if (nNodes <= 0) return;             // uniform per block
    int lo = blk * CAPB;
    int n  = min(cur[blk] - lo, CAPB);

    for (int i = tid; i < SUBDIV; i += 1024) cnt[i] = 0;
    __syncthreads();

    // ---- load records into regs + LDS hist ----
    int2 r[CAPB / 1024];
    #pragma unroll
    for (int k = 0; k < CAPB / 1024; ++k) {
        int i = k * 1024 + tid;
        if (i < n) { r[k] = buf[lo + i]; atomicAdd(&cnt[r[k].x >> 17], 1); }
        else r[k].x = -1;
    }
    __syncthreads();

    // ---- exclusive scan of node counts (SUBDIV <= 1024) ----
    int v = (tid < SUBDIV) ? cnt[tid] : 0;
    scn[tid] = v; __syncthreads();
    for (int off = 1; off < 1024; off <<= 1) {
        int x = scn[tid];
        if (tid >= off) x += scn[tid - off];
        __syncthreads(); scn[tid] = x; __syncthreads();
    }
    if (tid < SUBDIV) cnt[tid] = scn[tid] - v;   // exclusive -> cursor
    __syncthreads();

    // ---- place into LDS sorted array ----
    #pragma unroll
    for (int k = 0; k < CAPB / 1024; ++k) {
        if (r[k].x >= 0) {
            int p = atomicAdd(&cnt[r[k].x >> 17], 1);
            srt[p] = r[k];
        }
    }
    __syncthreads();                     // cnt[dl] now = inclusive end

    // ---- gather: one 16-lane quadrant per node ----
    int qd = tid >> 4;                   // 0..63
    int c4 = (tid & 15) << 2;
    for (int nl = qd; nl < nNodes; nl += 64) {
        int node = nodeLo + nl;
        if (FINE) {
            int iv = inv[node];
            if (iv >= 0) {               // injection: copy h row
                float4 vv = *(const float4*)(feat + (size_t)iv * C + c4);
                *(float4*)(outp + (size_t)node * C + c4) = vv;
                continue;
            }
        }
        int s = (nl == 0) ? 0 : cnt[nl - 1];
        int e = cnt[nl];
        float ax = 0.f, ay = 0.f, az = 0.f, aw = 0.f;
        for (int j = s; j < e; j += 4) {
            int2 q0 = srt[j];
            int2 q1 = (j + 1 < e) ? srt[j + 1] : make_int2(0, 0);
            int2 q2 = (j + 2 < e) ? srt[j + 2] : make_int2(0, 0);
            int2 q3 = (j + 3 < e) ? srt[j + 3] : make_int2(0, 0);
            float4 v0 = *(const float4*)(feat + (size_t)(q0.x & 0x1FFFF) * C + c4);
            float4 v1 = *(const float4*)(feat + (size_t)(q1.x & 0x1FFFF) * C + c4);
            float4 v2 = *(const float4*)(feat + (size_t)(q2.x & 0x1FFFF) * C + c4);
            float4 v3 = *(const float4*)(feat + (size_t)(q3.x & 0x1FFFF) * C + c4);
            float w0 = __int_as_float(q0.y), w1 = __int_as_float(q1.y);
            float w2 = __int_as_float(q2.y), w3 = __int_as_float(q3.y);
            ax = fmaf(w0, v0.x, ax); ay = fmaf(w0, v0.y, ay);
            az = fmaf(w0, v0.z, az); aw = fmaf(w0, v0.w, aw);
            ax = fmaf(w1, v1.x, ax); ay = fmaf(w1, v1.y, ay);
            az = fmaf(w1, v1.z, az); aw = fmaf(w1, v1.w, aw);
            ax = fmaf(w2, v2.x, ax); ay = fmaf(w2, v2.y, ay);
            az = fmaf(w2, v2.z, az); aw = fmaf(w2, v2.w, aw);
            ax = fmaf(w3, v3.x, ax); ay = fmaf(w3, v3.y, ay);
            az = fmaf(w3, v3.z, az); aw = fmaf(w3, v3.w, aw);
        }
        *(float4*)(outp + (size_t)node * C + c4) = make_float4(ax, ay, az, aw);
    }
}

// ---------------- GEMM / inv (unchanged, proven) ----------------
__global__ __launch_bounds__(256) void k_gemm_ip(
    float* __restrict__ h, const float* __restrict__ W, const float* __restrict__ b)
{
    int tid = threadIdx.x;
    int lane = tid & 63;
    float wreg[64];
    #pragma unroll
    for (int k = 0; k < 64; ++k) wreg[k] = W[k * C + lane];
    float bl = b[lane];
    int wv = (blockIdx.x * 256 + tid) >> 6;
    int nW = gridDim.x * 4;
    for (int row = wv; row < NC; row += nW) {
        float* ar = h + (size_t)row * C;
        float acc = bl;
        #pragma unroll
        for (int kk = 0; kk < 16; ++kk) {
            float4 a4 = *(const float4*)(ar + 4 * kk);
            acc = fmaf(a4.x, wreg[4 * kk + 0], acc);
            acc = fmaf(a4.y, wreg[4 * kk + 1], acc);
            acc = fmaf(a4.z, wreg[4 * kk + 2], acc);
            acc = fmaf(a4.w, wreg[4 * kk + 3], acc);
        }
        ar[lane] = acc;
    }
}

__global__ __launch_bounds__(256) void k_inv(
    const int* __restrict__ fwd, int* __restrict__ inv)
{
    int i = blockIdx.x * 256 + threadIdx.x;
    if (i < NC) inv[fwd[i]] = i;
}

extern "C" void kernel_launch(void* const* d_in, const int* in_sizes, int n_in,
                              void* d_out, int out_size, void* d_ws, size_t ws_size,
                              hipStream_t stream) {
    const float* x    = (const float*)d_in[0];
    const float* W    = (const float*)d_in[1];
    const float* b    = (const float*)d_in[2];
    const int*   ei   = (const int*)d_in[3];   // [2,E]: src = ei, dst = ei+NE
    const float* ea   = (const float*)d_in[4];
    const int*   psrc = (const int*)d_in[5];
    const int*   pdst = (const int*)d_in[6];
    const float* pw   = (const float*)d_in[7];
    const int*   fwd  = (const int*)d_in[8];
    float* out = (float*)d_out;

    // Workspace (~44 MB): h 25.6 | buf 16.8 | inv 1.6 | curC/curF
    char* p = (char*)d_ws;
    float* h   = (float*)p;  p += (size_t)NC * C * sizeof(float);        // 25.6 MB
    int2*  buf = (int2*)p;   p += (size_t)NSUB * CAPB * sizeof(int2);    // 16.8 MB
    int*   inv = (int*)p;    p += (size_t)NF * sizeof(int);              // 1.6 MB
    int*   curC = (int*)p;   p += NSUB * sizeof(int);
    int*   curF = (int*)p;   p += NSUB * sizeof(int);

    const int nTiles = (NE + 4095) / 4096;        // 391

    // cursors + inv map (independent of partitions)
    k_curinit<<<1, 1024, 0, stream>>>(curC, curF);
    hipMemsetAsync(inv, 0xFF, (size_t)NF * sizeof(int), stream);
    k_inv<<<(NC + 255) / 256, 256, 0, stream>>>(fwd, inv);

    // ---- coarse: partition -> fused sort+gather (agg -> h), then GEMM ----
    k_partition<SUBC><<<nTiles, 256, 0, stream>>>(ei + NE, ei, ea, curC, buf);
    k_sortgather<SUBC, NC, false><<<NSUB, 1024, 0, stream>>>(
        buf, curC, x, nullptr, h);
    k_gemm_ip<<<2048, 256, 0, stream>>>(h, W, b);

    // ---- fine: partition (reuses buf) -> fused sort+gather+inject -> out ----
    k_partition<SUBF><<<nTiles, 256, 0, stream>>>(pdst, psrc, pw, curF, buf);
    k_sortgather<SUBF, NF, true><<<NSUB, 1024, 0, stream>>>(
        buf, curF, h, inv, out);
}

// Round 5
// 363.458 us; speedup vs baseline: 2.0069x; 1.0366x over previous
//
#include <hip/hip_runtime.h>

#define NC 100000
#define NF 400000
#define NE 1600000
#define C  64

// ============================================================================
// v6: v5 + fixed GEMM register allocation + one fewer dispatch.
//  k_partition  : 512-way dst-range split; record packed to 8B:
//                 {dl<<17 | src, w}. Cursors are zero-based deltas
//                 (pos = bk*CAPB + atomicAdd) so they memset/zero trivially.
//  k_sortgather : ONE BLOCK PER BUCKET (512 blocks, 1024 thr).
//                 Records -> regs, LDS hist + scan, place into LDS sorted
//                 array (32KB), gather with one 16-lane quadrant per node.
//  k_gemm_ip    : __launch_bounds__(256, 1) pins the 64-float W column in
//                 VGPRs (round-4 counters showed VGPR=40 -> W reloaded from
//                 L1 every row, 67us for a 38MB op). 2-row ILP to overlap
//                 wave-uniform row-load latency.
// ============================================================================

#define NSUB 512                // buckets per phase
#define CAPB 4096               // records per bucket (mean ~3130)
#define SUBC 196                // dst nodes per coarse bucket
#define SUBF 782                // dst nodes per fine bucket

template<int SUBDIV>
__global__ __launch_bounds__(256) void k_partition(
    const int* __restrict__ dst, const int* __restrict__ src,
    const float* __restrict__ w, int* __restrict__ cur, int2* __restrict__ buf)
{
    __shared__ int lcnt[NSUB];
    int tid = threadIdx.x;
    int e0 = blockIdx.x * 4096;
    for (int i = tid; i < NSUB; i += 256) lcnt[i] = 0;
    __syncthreads();
    int rb[16]; int2 rv[16];
    #pragma unroll
    for (int i = 0; i < 16; ++i) {
        int e = e0 + i * 256 + tid;
        if (e < NE) {
            int d  = dst[e];
            int bk = d / SUBDIV;
            rb[i]  = bk;
            rv[i]  = make_int2(((d - bk * SUBDIV) << 17) | src[e],
                               __float_as_int(w[e]));
            atomicAdd(&lcnt[bk], 1);
        } else rb[i] = -1;
    }
    __syncthreads();
    for (int i = tid; i < NSUB; i += 256)
        lcnt[i] = i * CAPB + atomicAdd(&cur[i], lcnt[i]);
    __syncthreads();
    #pragma unroll
    for (int i = 0; i < 16; ++i) {
        if (rb[i] >= 0) {
            int p = atomicAdd(&lcnt[rb[i]], 1);
            if (p < (rb[i] + 1) * CAPB) buf[p] = rv[i];   // overflow guard
        }
    }
}

// Block = bucket. LDS sort + direct gather; no global CSR.
template<int SUBDIV, int NTOT, bool FINE>
__global__ __launch_bounds__(1024, 8) void k_sortgather(
    const int2* __restrict__ buf, const int* __restrict__ cur,
    const float* __restrict__ feat,      // x (coarse) or h (fine)
    const int* __restrict__ inv,         // fine only
    float* __restrict__ outp)            // h/agg (coarse) or out (fine)
{
    __shared__ int2 srt[CAPB];           // 32 KB sorted records
    __shared__ int  cnt[SUBDIV];         // per-node cursor/end
    __shared__ int  scn[1024];
    int tid = threadIdx.x;
    int blk = blockIdx.x;
    int nodeLo = blk * SUBDIV;
    int nNodes = min(SUBDIV, NTOT - nodeLo);
    if (nNodes <= 0) return;             // uniform per block
    int lo = blk * CAPB;
    int n  = min(cur[blk], CAPB);        // cur now holds the count directly

    for (int i = tid; i < SUBDIV; i += 1024) cnt[i] = 0;
    __syncthreads();

    // ---- load records into regs + LDS hist ----
    int2 r[CAPB / 1024];
    #pragma unroll
    for (int k = 0; k < CAPB / 1024; ++k) {
        int i = k * 1024 + tid;
        if (i < n) { r[k] = buf[lo + i]; atomicAdd(&cnt[r[k].x >> 17], 1); }
        else r[k].x = -1;
    }
    __syncthreads();

    // ---- exclusive scan of node counts (SUBDIV <= 1024) ----
    int v = (tid < SUBDIV) ? cnt[tid] : 0;
    scn[tid] = v; __syncthreads();
    for (int off = 1; off < 1024; off <<= 1) {
        int x = scn[tid];
        if (tid >= off) x += scn[tid - off];
        __syncthreads(); scn[tid] = x; __syncthreads();
    }
    if (tid < SUBDIV) cnt[tid] = scn[tid] - v;   // exclusive -> cursor
    __syncthreads();

    // ---- place into LDS sorted array ----
    #pragma unroll
    for (int k = 0; k < CAPB / 1024; ++k) {
        if (r[k].x >= 0) {
            int p = atomicAdd(&cnt[r[k].x >> 17], 1);
            srt[p] = r[k];
        }
    }
    __syncthreads();                     // cnt[dl] now = inclusive end

    // ---- gather: one 16-lane quadrant per node ----
    int qd = tid >> 4;                   // 0..63
    int c4 = (tid & 15) << 2;
    for (int nl = qd; nl < nNodes; nl += 64) {
        int node = nodeLo + nl;
        if (FINE) {
            int iv = inv[node];
            if (iv >= 0) {               // injection: copy h row
                float4 vv = *(const float4*)(feat + (size_t)iv * C + c4);
                *(float4*)(outp + (size_t)node * C + c4) = vv;
                continue;
            }
        }
        int s = (nl == 0) ? 0 : cnt[nl - 1];
        int e = cnt[nl];
        float ax = 0.f, ay = 0.f, az = 0.f, aw = 0.f;
        for (int j = s; j < e; j += 4) {
            int2 q0 = srt[j];
            int2 q1 = (j + 1 < e) ? srt[j + 1] : make_int2(0, 0);
            int2 q2 = (j + 2 < e) ? srt[j + 2] : make_int2(0, 0);
            int2 q3 = (j + 3 < e) ? srt[j + 3] : make_int2(0, 0);
            float4 v0 = *(const float4*)(feat + (size_t)(q0.x & 0x1FFFF) * C + c4);
            float4 v1 = *(const float4*)(feat + (size_t)(q1.x & 0x1FFFF) * C + c4);
            float4 v2 = *(const float4*)(feat + (size_t)(q2.x & 0x1FFFF) * C + c4);
            float4 v3 = *(const float4*)(feat + (size_t)(q3.x & 0x1FFFF) * C + c4);
            float w0 = __int_as_float(q0.y), w1 = __int_as_float(q1.y);
            float w2 = __int_as_float(q2.y), w3 = __int_as_float(q3.y);
            ax = fmaf(w0, v0.x, ax); ay = fmaf(w0, v0.y, ay);
            az = fmaf(w0, v0.z, az); aw = fmaf(w0, v0.w, aw);
            ax = fmaf(w1, v1.x, ax); ay = fmaf(w1, v1.y, ay);
            az = fmaf(w1, v1.z, az); aw = fmaf(w1, v1.w, aw);
            ax = fmaf(w2, v2.x, ax); ay = fmaf(w2, v2.y, ay);
            az = fmaf(w2, v2.z, az); aw = fmaf(w2, v2.w, aw);
            ax = fmaf(w3, v3.x, ax); ay = fmaf(w3, v3.y, ay);
            az = fmaf(w3, v3.z, az); aw = fmaf(w3, v3.w, aw);
        }
        *(float4*)(outp + (size_t)node * C + c4) = make_float4(ax, ay, az, aw);
    }
}

// GEMM: (256,1) -> allocator may keep wreg[64] resident (round-4 failure
// mode: VGPR=40, W reloaded per row). 2 independent rows in flight.
__global__ __launch_bounds__(256, 1) void k_gemm_ip(
    float* __restrict__ h, const float* __restrict__ W, const float* __restrict__ b)
{
    int tid = threadIdx.x;
    int lane = tid & 63;
    float wreg[64];
    #pragma unroll
    for (int k = 0; k < 64; ++k) wreg[k] = W[k * C + lane];
    float bl = b[lane];
    int wv = (blockIdx.x * 256 + tid) >> 6;
    int nW = gridDim.x * 4;
    for (int row = wv; row < NC; row += 2 * nW) {
        int row2 = row + nW;
        bool has2 = row2 < NC;
        int row2c = has2 ? row2 : row;           // safe dup-load on tail
        float* ar  = h + (size_t)row * C;
        float* ar2 = h + (size_t)row2c * C;
        float acc = bl, acc2 = bl;
        #pragma unroll
        for (int kk = 0; kk < 16; ++kk) {
            float4 a4 = *(const float4*)(ar + 4 * kk);
            float4 b4 = *(const float4*)(ar2 + 4 * kk);
            acc  = fmaf(a4.x, wreg[4 * kk + 0], acc);
            acc  = fmaf(a4.y, wreg[4 * kk + 1], acc);
            acc  = fmaf(a4.z, wreg[4 * kk + 2], acc);
            acc  = fmaf(a4.w, wreg[4 * kk + 3], acc);
            acc2 = fmaf(b4.x, wreg[4 * kk + 0], acc2);
            acc2 = fmaf(b4.y, wreg[4 * kk + 1], acc2);
            acc2 = fmaf(b4.z, wreg[4 * kk + 2], acc2);
            acc2 = fmaf(b4.w, wreg[4 * kk + 3], acc2);
        }
        ar[lane] = acc;
        if (has2) ar2[lane] = acc2;
    }
}

// inv scatter + zero both cursor arrays (block 0) — replaces k_curinit.
__global__ __launch_bounds__(256) void k_inv(
    const int* __restrict__ fwd, int* __restrict__ inv, int* __restrict__ cur)
{
    int i = blockIdx.x * 256 + threadIdx.x;
    if (i < NC) inv[fwd[i]] = i;
    if (blockIdx.x == 0)
        for (int j = threadIdx.x; j < 2 * NSUB; j += 256) cur[j] = 0;
}

extern "C" void kernel_launch(void* const* d_in, const int* in_sizes, int n_in,
                              void* d_out, int out_size, void* d_ws, size_t ws_size,
                              hipStream_t stream) {
    const float* x    = (const float*)d_in[0];
    const float* W    = (const float*)d_in[1];
    const float* b    = (const float*)d_in[2];
    const int*   ei   = (const int*)d_in[3];   // [2,E]: src = ei, dst = ei+NE
    const float* ea   = (const float*)d_in[4];
    const int*   psrc = (const int*)d_in[5];
    const int*   pdst = (const int*)d_in[6];
    const float* pw   = (const float*)d_in[7];
    const int*   fwd  = (const int*)d_in[8];
    float* out = (float*)d_out;

    // Workspace (~44 MB): h 25.6 | buf 16.8 | inv 1.6 | curC+curF (adjacent)
    char* p = (char*)d_ws;
    float* h   = (float*)p;  p += (size_t)NC * C * sizeof(float);        // 25.6 MB
    int2*  buf = (int2*)p;   p += (size_t)NSUB * CAPB * sizeof(int2);    // 16.8 MB
    int*   inv = (int*)p;    p += (size_t)NF * sizeof(int);              // 1.6 MB
    int*   curC = (int*)p;   p += NSUB * sizeof(int);
    int*   curF = (int*)p;   p += NSUB * sizeof(int);

    const int nTiles = (NE + 4095) / 4096;        // 391

    // inv map + cursor zeroing (one dispatch)
    hipMemsetAsync(inv, 0xFF, (size_t)NF * sizeof(int), stream);
    k_inv<<<(NC + 255) / 256, 256, 0, stream>>>(fwd, inv, curC);

    // ---- coarse: partition -> fused sort+gather (agg -> h), then GEMM ----
    k_partition<SUBC><<<nTiles, 256, 0, stream>>>(ei + NE, ei, ea, curC, buf);
    k_sortgather<SUBC, NC, false><<<NSUB, 1024, 0, stream>>>(
        buf, curC, x, nullptr, h);
    k_gemm_ip<<<2048, 256, 0, stream>>>(h, W, b);

    // ---- fine: partition (reuses buf) -> fused sort+gather+inject -> out ----
    k_partition<SUBF><<<nTiles, 256, 0, stream>>>(pdst, psrc, pw, curF, buf);
    k_sortgather<SUBF, NF, true><<<NSUB, 1024, 0, stream>>>(
        buf, curF, h, inv, out);
}